// Round 1
// baseline (1787.630 us; speedup 1.0000x reference)
//
#include <hip/hip_runtime.h>
#include <stdint.h>

// ---------------- problem constants (fixed by setup_inputs) ----------------
#define NROWS  16384      // B*S = 4*4096
#define DMODEL 2048       // D
#define DIN    4096       // 2*D
#define NEXP   3
#define NG     (NROWS*NEXP)   // 49152 gumbel samples

// ---------------- workspace layout (bytes) ----------------
#define WS_CNT   0        // 4 ints: expert counts (cnt[2] doubles as rowlist slot ctr)
#define WS_BF    256      // 3 floats: fused bias
#define WS_WF    512      // 4096*3 floats = 49152 B
#define WS_GUM   65536    // 49152 floats = 196608 B
#define WS_ROWL  262144   // 16384 ints

// JAX default since ~0.4.36 is threefry_partitionable=True (per-element u64
// counter, 32-bit out = x0^x1). If validation fails with ~2/3 of rows wrong,
// flip this to 0 (legacy split-iota variant).
#define THREEFRY_PARTITIONABLE 1

__device__ __forceinline__ void tf2x32(uint32_t k0, uint32_t k1,
                                       uint32_t x0, uint32_t x1,
                                       uint32_t& o0, uint32_t& o1) {
  uint32_t k2 = k0 ^ k1 ^ 0x1BD11BDAu;
  x0 += k0; x1 += k1;
#define TFR(r) { x0 += x1; x1 = (x1 << r) | (x1 >> (32 - r)); x1 ^= x0; }
  TFR(13) TFR(15) TFR(26) TFR(6)
  x0 += k1; x1 += k2 + 1u;
  TFR(17) TFR(29) TFR(16) TFR(24)
  x0 += k2; x1 += k0 + 2u;
  TFR(13) TFR(15) TFR(26) TFR(6)
  x0 += k0; x1 += k1 + 3u;
  TFR(17) TFR(29) TFR(16) TFR(24)
  x0 += k1; x1 += k2 + 4u;
  TFR(13) TFR(15) TFR(26) TFR(6)
  x0 += k2; x1 += k0 + 5u;
#undef TFR
  o0 = x0; o1 = x1;
}

__global__ void k_init(int* __restrict__ cnt) {
  if (threadIdx.x < 8) cnt[threadIdx.x] = 0;
}

// Reproduce jax.random.uniform(key(42), (4,4096,3)) -> gumbel = -log(-log(clip(U)))
__global__ void k_gumbel(float* __restrict__ g) {
  int j = blockIdx.x * blockDim.x + threadIdx.x;
  if (j >= NG) return;
  uint32_t b0, b1, bits;
#if THREEFRY_PARTITIONABLE
  tf2x32(0u, 42u, 0u, (uint32_t)j, b0, b1);   // counter = u64 flat index (hi=0, lo=j)
  bits = b0 ^ b1;
#else
  const int half = NG / 2;
  if (j < half) { tf2x32(0u, 42u, (uint32_t)j, (uint32_t)(j + half), b0, b1); bits = b0; }
  else          { tf2x32(0u, 42u, (uint32_t)(j - half), (uint32_t)j, b0, b1); bits = b1; }
#endif
  float U = __uint_as_float((bits >> 9) | 0x3f800000u) - 1.0f;  // [0,1)
  U = fmaxf(U, 1e-10f);            // clip(EPS_U, 1.0)
  U = fminf(U, 1.0f);
  g[j] = -logf(-logf(U));
}

// W_fused[k][e] = sum_d W_share[k][d]*W_router[d][e]; block 4096 does b_fused.
__global__ __launch_bounds__(256)
void k_wfused(const float* __restrict__ Ws, const float* __restrict__ bsh,
              const float* __restrict__ Wr, const float* __restrict__ br,
              float* __restrict__ Wf, float* __restrict__ bf) {
  const int k = blockIdx.x;               // 0..4096 (4096 => bias)
  const int t = threadIdx.x;
  const float* src = (k < DIN) ? (Ws + (size_t)k * DMODEL) : bsh;
  float4 x0 = *(const float4*)(src + t * 8);
  float4 x1 = *(const float4*)(src + t * 8 + 4);
  float xv[8] = {x0.x, x0.y, x0.z, x0.w, x1.x, x1.y, x1.z, x1.w};
  float4 w4[6];
  const float4* wp = (const float4*)(Wr + t * 24);   // 8 d's * 3 experts, contiguous
#pragma unroll
  for (int i = 0; i < 6; ++i) w4[i] = wp[i];
  const float* wfv = (const float*)w4;
  float z0 = 0.f, z1 = 0.f, z2 = 0.f;
#pragma unroll
  for (int jj = 0; jj < 8; ++jj) {
    z0 = fmaf(xv[jj], wfv[jj*3+0], z0);
    z1 = fmaf(xv[jj], wfv[jj*3+1], z1);
    z2 = fmaf(xv[jj], wfv[jj*3+2], z2);
  }
#pragma unroll
  for (int off = 32; off > 0; off >>= 1) {
    z0 += __shfl_down(z0, off, 64);
    z1 += __shfl_down(z1, off, 64);
    z2 += __shfl_down(z2, off, 64);
  }
  __shared__ float red[4][3];
  int lane = t & 63, wv = t >> 6;
  if (lane == 0) { red[wv][0] = z0; red[wv][1] = z1; red[wv][2] = z2; }
  __syncthreads();
  if (t == 0) {
    float s0 = red[0][0] + red[1][0] + red[2][0] + red[3][0];
    float s1 = red[0][1] + red[1][1] + red[2][1] + red[3][1];
    float s2 = red[0][2] + red[1][2] + red[2][2] + red[3][2];
    if (k < DIN) { Wf[k*3+0] = s0; Wf[k*3+1] = s1; Wf[k*3+2] = s2; }
    else { bf[0] = s0 + br[0]; bf[1] = s1 + br[1]; bf[2] = s2 + br[2]; }
  }
}

// Per row: logits = [attn1|attn2] . W_fused + b_fused + gumbel; argmax (first-max
// tie-break). idx 0/1: write the candidate row (already in registers). idx 2:
// append row to rowlist for the GEMM.
#define RPB 8
__global__ __launch_bounds__(256)
void k_router(const float* __restrict__ a1, const float* __restrict__ a2,
              const float* __restrict__ Wf, const float* __restrict__ bf,
              const float* __restrict__ gum,
              float* __restrict__ out, int* __restrict__ cnt,
              int* __restrict__ rowl) {
  const int t = threadIdx.x;
  float wA[24], wB[24];
  {
    float4 q[6];
    const float4* p = (const float4*)(Wf + t * 24);
#pragma unroll
    for (int i = 0; i < 6; ++i) q[i] = p[i];
#pragma unroll
    for (int i = 0; i < 24; ++i) wA[i] = ((const float*)q)[i];
    const float4* p2 = (const float4*)(Wf + (size_t)DMODEL * 3 + t * 24);
#pragma unroll
    for (int i = 0; i < 6; ++i) q[i] = p2[i];
#pragma unroll
    for (int i = 0; i < 24; ++i) wB[i] = ((const float*)q)[i];
  }
  const float bf0 = bf[0], bf1 = bf[1], bf2 = bf[2];
  __shared__ float red[4][3];
  __shared__ int s_idx;
  const int lane = t & 63, wv = t >> 6;

  for (int rr = 0; rr < RPB; ++rr) {
    const int row = blockIdx.x * RPB + rr;
    const float* pa = a1 + (size_t)row * DMODEL + t * 8;
    const float* pb = a2 + (size_t)row * DMODEL + t * 8;
    float4 av0 = *(const float4*)pa, av1 = *(const float4*)(pa + 4);
    float4 bv0 = *(const float4*)pb, bv1 = *(const float4*)(pb + 4);
    float avv[8] = {av0.x, av0.y, av0.z, av0.w, av1.x, av1.y, av1.z, av1.w};
    float bvv[8] = {bv0.x, bv0.y, bv0.z, bv0.w, bv1.x, bv1.y, bv1.z, bv1.w};
    float z0 = 0.f, z1 = 0.f, z2 = 0.f;
#pragma unroll
    for (int jj = 0; jj < 8; ++jj) {
      z0 = fmaf(avv[jj], wA[jj*3+0], z0);
      z1 = fmaf(avv[jj], wA[jj*3+1], z1);
      z2 = fmaf(avv[jj], wA[jj*3+2], z2);
    }
#pragma unroll
    for (int jj = 0; jj < 8; ++jj) {
      z0 = fmaf(bvv[jj], wB[jj*3+0], z0);
      z1 = fmaf(bvv[jj], wB[jj*3+1], z1);
      z2 = fmaf(bvv[jj], wB[jj*3+2], z2);
    }
#pragma unroll
    for (int off = 32; off > 0; off >>= 1) {
      z0 += __shfl_down(z0, off, 64);
      z1 += __shfl_down(z1, off, 64);
      z2 += __shfl_down(z2, off, 64);
    }
    if (lane == 0) { red[wv][0] = z0; red[wv][1] = z1; red[wv][2] = z2; }
    __syncthreads();
    if (t == 0) {
      float l0 = red[0][0] + red[1][0] + red[2][0] + red[3][0] + bf0 + gum[row*3+0];
      float l1 = red[0][1] + red[1][1] + red[2][1] + red[3][1] + bf1 + gum[row*3+1];
      float l2 = red[0][2] + red[1][2] + red[2][2] + red[3][2] + bf2 + gum[row*3+2];
      int idx = 0; float m = l0;
      if (l1 > m) { m = l1; idx = 1; }
      if (l2 > m) { m = l2; idx = 2; }
      s_idx = idx;
      int pos = atomicAdd(&cnt[idx], 1);
      if (idx == 2) rowl[pos] = row;
    }
    __syncthreads();
    const int idx = s_idx;
    float* po = out + (size_t)row * DMODEL + t * 8;
    if (idx == 0)      { *(float4*)po = av0; *(float4*)(po + 4) = av1; }
    else if (idx == 1) { *(float4*)po = bv0; *(float4*)(po + 4) = bv1; }
    __syncthreads();   // protect red/s_idx reuse across rows
  }
}

// fp32 GEMM over selected rows only: out[row] = combined[row] @ W_share + b_share
// 128x128 tile, BK=32, 256 threads, 8x8 per thread.
#define BM 128
#define BN 128
#define BK 32
__global__ __launch_bounds__(256)
void k_gemm(const float* __restrict__ a1, const float* __restrict__ a2,
            const float* __restrict__ Ws, const float* __restrict__ bsh,
            const int* __restrict__ cnt, const int* __restrict__ rowl,
            float* __restrict__ out) {
  const int M = cnt[2];
  const int bm = blockIdx.x;
  if (bm * BM >= M) return;
  const int bn = blockIdx.y;
  __shared__ float As[BK][132];   // [k][m], +4 pad to spread write banks
  __shared__ float Bs[BK][128];   // [k][n]
  __shared__ int rows[BM];
  const int t = threadIdx.x;
  if (t < BM) {
    int i = bm * BM + t;
    rows[t] = (i < M) ? rowl[i] : -1;
  }
  __syncthreads();
  float acc[8][8];
#pragma unroll
  for (int i = 0; i < 8; ++i)
#pragma unroll
    for (int j = 0; j < 8; ++j) acc[i][j] = 0.f;
  const int tx = t & 15, ty = t >> 4;

  for (int k0 = 0; k0 < DIN; k0 += BK) {
    const float* Abase = (k0 < DMODEL) ? a1 : a2;
    const int kb = (k0 < DMODEL) ? k0 : (k0 - DMODEL);
    float4 av[4], bv4[4];
#pragma unroll
    for (int r = 0; r < 4; ++r) {           // A: 128 rows x 32 k
      int lin = r * 256 + t;
      int mi = lin >> 3;
      int ki = (lin & 7) << 2;
      int row = rows[mi];
      av[r] = (row >= 0) ? *(const float4*)(Abase + (size_t)row * DMODEL + kb + ki)
                         : make_float4(0.f, 0.f, 0.f, 0.f);
    }
#pragma unroll
    for (int r = 0; r < 4; ++r) {           // B: 32 k x 128 n
      int lin = r * 256 + t;
      int ki = lin >> 5;
      int ni = (lin & 31) << 2;
      bv4[r] = *(const float4*)(Ws + (size_t)(k0 + ki) * DMODEL + bn * BN + ni);
    }
    __syncthreads();                        // prior compute done before overwrite
#pragma unroll
    for (int r = 0; r < 4; ++r) {
      int lin = r * 256 + t;
      int mi = lin >> 3;
      int ki = (lin & 7) << 2;
      As[ki + 0][mi] = av[r].x;
      As[ki + 1][mi] = av[r].y;
      As[ki + 2][mi] = av[r].z;
      As[ki + 3][mi] = av[r].w;
      int k2 = lin >> 5;
      int ni = (lin & 31) << 2;
      *(float4*)(&Bs[k2][ni]) = bv4[r];
    }
    __syncthreads();
#pragma unroll
    for (int kk = 0; kk < BK; ++kk) {
      float4 aL = *(const float4*)(&As[kk][ty << 2]);
      float4 aH = *(const float4*)(&As[kk][64 + (ty << 2)]);
      float4 bL = *(const float4*)(&Bs[kk][tx << 2]);
      float4 bH = *(const float4*)(&Bs[kk][64 + (tx << 2)]);
      float am[8] = {aL.x, aL.y, aL.z, aL.w, aH.x, aH.y, aH.z, aH.w};
      float bb[8] = {bL.x, bL.y, bL.z, bL.w, bH.x, bH.y, bH.z, bH.w};
#pragma unroll
      for (int i = 0; i < 8; ++i)
#pragma unroll
        for (int j = 0; j < 8; ++j)
          acc[i][j] = fmaf(am[i], bb[j], acc[i][j]);
    }
  }
  float bias[8];
#pragma unroll
  for (int j = 0; j < 4; ++j) {
    bias[j]     = bsh[bn * BN + (tx << 2) + j];
    bias[4 + j] = bsh[bn * BN + 64 + (tx << 2) + j];
  }
#pragma unroll
  for (int i = 0; i < 8; ++i) {
    int m = (i < 4) ? ((ty << 2) + i) : (64 + (ty << 2) + (i - 4));
    int row = rows[m];
    if (row < 0) continue;
    float* po = out + (size_t)row * DMODEL + bn * BN;
    float4 v0 = make_float4(acc[i][0] + bias[0], acc[i][1] + bias[1],
                            acc[i][2] + bias[2], acc[i][3] + bias[3]);
    float4 v1 = make_float4(acc[i][4] + bias[4], acc[i][5] + bias[5],
                            acc[i][6] + bias[6], acc[i][7] + bias[7]);
    *(float4*)(po + (tx << 2)) = v0;
    *(float4*)(po + 64 + (tx << 2)) = v1;
  }
}

// p is exactly one-hot => entropy term is exactly 0 (f32(1+1e-8)==1);
// load balance from the 3 counts.
__global__ void k_loss(const int* __restrict__ cnt, float* __restrict__ o) {
  if (threadIdx.x == 0 && blockIdx.x == 0) {
    const float inv = 1.0f / (float)NROWS;
    float lb = 0.f;
#pragma unroll
    for (int e = 0; e < 3; ++e) {
      float m = (float)cnt[e] * inv;
      lb -= m * logf(m + 1e-8f);
    }
    o[0] = 0.0f;   // entropy_loss
    o[1] = lb;     // load_balance_loss
  }
}

extern "C" void kernel_launch(void* const* d_in, const int* in_sizes, int n_in,
                              void* d_out, int out_size, void* d_ws, size_t ws_size,
                              hipStream_t stream) {
  const float* a1  = (const float*)d_in[0];
  const float* a2  = (const float*)d_in[1];
  const float* Ws  = (const float*)d_in[2];
  const float* bsh = (const float*)d_in[3];
  const float* Wr  = (const float*)d_in[4];
  const float* br  = (const float*)d_in[5];
  float* out = (float*)d_out;
  char* ws = (char*)d_ws;
  int*   cnt  = (int*)(ws + WS_CNT);
  float* bf   = (float*)(ws + WS_BF);
  float* Wf   = (float*)(ws + WS_WF);
  float* gum  = (float*)(ws + WS_GUM);
  int*   rowl = (int*)(ws + WS_ROWL);
  float* losses = out + (size_t)NROWS * DMODEL;

  hipLaunchKernelGGL(k_init,   dim3(1),               dim3(64),  0, stream, cnt);
  hipLaunchKernelGGL(k_gumbel, dim3((NG + 255)/256),  dim3(256), 0, stream, gum);
  hipLaunchKernelGGL(k_wfused, dim3(DIN + 1),         dim3(256), 0, stream, Ws, bsh, Wr, br, Wf, bf);
  hipLaunchKernelGGL(k_router, dim3(NROWS / RPB),     dim3(256), 0, stream, a1, a2, Wf, bf, gum, out, cnt, rowl);
  hipLaunchKernelGGL(k_gemm,   dim3(NROWS / BM, DMODEL / BN), dim3(256), 0, stream, a1, a2, Ws, bsh, cnt, rowl, out);
  hipLaunchKernelGGL(k_loss,   dim3(1),               dim3(64),  0, stream, cnt, losses);
}

// Round 2
// 613.791 us; speedup vs baseline: 2.9124x; 2.9124x over previous
//
#include <hip/hip_runtime.h>
#include <stdint.h>

// ---------------- problem constants ----------------
#define NROWS  16384      // B*S
#define DMODEL 2048
#define DIN    4096
#define NG     (NROWS*3)

// ---------------- workspace layout (bytes) ----------------
#define WS_CNT   0
#define WS_BF    256
#define WS_WF    512
#define WS_GUM   65536
#define WS_ROWL  262144
#define WS_WTH   (1u<<20)                 // W^T hi bf16 [2048][4096] (swizzled)
#define WS_WTL   (WS_WTH + 16777216u)     // W^T lo bf16
#define WS_NEED  ((size_t)WS_WTL + 16777216u)

typedef __attribute__((ext_vector_type(8))) short short8;
typedef __attribute__((ext_vector_type(4))) float f32x4;

#define THREEFRY_PARTITIONABLE 1

__device__ __forceinline__ void tf2x32(uint32_t k0, uint32_t k1,
                                       uint32_t x0, uint32_t x1,
                                       uint32_t& o0, uint32_t& o1) {
  uint32_t k2 = k0 ^ k1 ^ 0x1BD11BDAu;
  x0 += k0; x1 += k1;
#define TFR(r) { x0 += x1; x1 = (x1 << r) | (x1 >> (32 - r)); x1 ^= x0; }
  TFR(13) TFR(15) TFR(26) TFR(6)
  x0 += k1; x1 += k2 + 1u;
  TFR(17) TFR(29) TFR(16) TFR(24)
  x0 += k2; x1 += k0 + 2u;
  TFR(13) TFR(15) TFR(26) TFR(6)
  x0 += k0; x1 += k1 + 3u;
  TFR(17) TFR(29) TFR(16) TFR(24)
  x0 += k1; x1 += k2 + 4u;
  TFR(13) TFR(15) TFR(26) TFR(6)
  x0 += k2; x1 += k0 + 5u;
#undef TFR
  o0 = x0; o1 = x1;
}

__global__ void k_init(int* __restrict__ cnt) {
  if (threadIdx.x < 8) cnt[threadIdx.x] = 0;
}

__global__ void k_gumbel(float* __restrict__ g) {
  int j = blockIdx.x * blockDim.x + threadIdx.x;
  if (j >= NG) return;
  uint32_t b0, b1, bits;
#if THREEFRY_PARTITIONABLE
  tf2x32(0u, 42u, 0u, (uint32_t)j, b0, b1);
  bits = b0 ^ b1;
#else
  const int half = NG / 2;
  if (j < half) { tf2x32(0u, 42u, (uint32_t)j, (uint32_t)(j + half), b0, b1); bits = b0; }
  else          { tf2x32(0u, 42u, (uint32_t)(j - half), (uint32_t)j, b0, b1); bits = b1; }
#endif
  float U = __uint_as_float((bits >> 9) | 0x3f800000u) - 1.0f;
  U = fmaxf(U, 1e-10f);
  U = fminf(U, 1.0f);
  g[j] = -logf(-logf(U));
}

__global__ __launch_bounds__(256)
void k_wfused(const float* __restrict__ Ws, const float* __restrict__ bsh,
              const float* __restrict__ Wr, const float* __restrict__ br,
              float* __restrict__ Wf, float* __restrict__ bf) {
  const int k = blockIdx.x;
  const int t = threadIdx.x;
  const float* src = (k < DIN) ? (Ws + (size_t)k * DMODEL) : bsh;
  float4 x0 = *(const float4*)(src + t * 8);
  float4 x1 = *(const float4*)(src + t * 8 + 4);
  float xv[8] = {x0.x, x0.y, x0.z, x0.w, x1.x, x1.y, x1.z, x1.w};
  float4 w4[6];
  const float4* wp = (const float4*)(Wr + t * 24);
#pragma unroll
  for (int i = 0; i < 6; ++i) w4[i] = wp[i];
  const float* wfv = (const float*)w4;
  float z0 = 0.f, z1 = 0.f, z2 = 0.f;
#pragma unroll
  for (int jj = 0; jj < 8; ++jj) {
    z0 = fmaf(xv[jj], wfv[jj*3+0], z0);
    z1 = fmaf(xv[jj], wfv[jj*3+1], z1);
    z2 = fmaf(xv[jj], wfv[jj*3+2], z2);
  }
#pragma unroll
  for (int off = 32; off > 0; off >>= 1) {
    z0 += __shfl_down(z0, off, 64);
    z1 += __shfl_down(z1, off, 64);
    z2 += __shfl_down(z2, off, 64);
  }
  __shared__ float red[4][3];
  int lane = t & 63, wv = t >> 6;
  if (lane == 0) { red[wv][0] = z0; red[wv][1] = z1; red[wv][2] = z2; }
  __syncthreads();
  if (t == 0) {
    float s0 = red[0][0] + red[1][0] + red[2][0] + red[3][0];
    float s1 = red[0][1] + red[1][1] + red[2][1] + red[3][1];
    float s2 = red[0][2] + red[1][2] + red[2][2] + red[3][2];
    if (k < DIN) { Wf[k*3+0] = s0; Wf[k*3+1] = s1; Wf[k*3+2] = s2; }
    else { bf[0] = s0 + br[0]; bf[1] = s1 + br[1]; bf[2] = s2 + br[2]; }
  }
}

#define RPB 8
__global__ __launch_bounds__(256)
void k_router(const float* __restrict__ a1, const float* __restrict__ a2,
              const float* __restrict__ Wf, const float* __restrict__ bf,
              const float* __restrict__ gum,
              float* __restrict__ out, int* __restrict__ cnt,
              int* __restrict__ rowl) {
  const int t = threadIdx.x;
  float wA[24], wB[24];
  {
    float4 q[6];
    const float4* p = (const float4*)(Wf + t * 24);
#pragma unroll
    for (int i = 0; i < 6; ++i) q[i] = p[i];
#pragma unroll
    for (int i = 0; i < 24; ++i) wA[i] = ((const float*)q)[i];
    const float4* p2 = (const float4*)(Wf + (size_t)DMODEL * 3 + t * 24);
#pragma unroll
    for (int i = 0; i < 6; ++i) q[i] = p2[i];
#pragma unroll
    for (int i = 0; i < 24; ++i) wB[i] = ((const float*)q)[i];
  }
  const float bf0 = bf[0], bf1 = bf[1], bf2 = bf[2];
  __shared__ float red[4][3];
  __shared__ int s_idx;
  const int lane = t & 63, wv = t >> 6;

  for (int rr = 0; rr < RPB; ++rr) {
    const int row = blockIdx.x * RPB + rr;
    const float* pa = a1 + (size_t)row * DMODEL + t * 8;
    const float* pb = a2 + (size_t)row * DMODEL + t * 8;
    float4 av0 = *(const float4*)pa, av1 = *(const float4*)(pa + 4);
    float4 bv0 = *(const float4*)pb, bv1 = *(const float4*)(pb + 4);
    float avv[8] = {av0.x, av0.y, av0.z, av0.w, av1.x, av1.y, av1.z, av1.w};
    float bvv[8] = {bv0.x, bv0.y, bv0.z, bv0.w, bv1.x, bv1.y, bv1.z, bv1.w};
    float z0 = 0.f, z1 = 0.f, z2 = 0.f;
#pragma unroll
    for (int jj = 0; jj < 8; ++jj) {
      z0 = fmaf(avv[jj], wA[jj*3+0], z0);
      z1 = fmaf(avv[jj], wA[jj*3+1], z1);
      z2 = fmaf(avv[jj], wA[jj*3+2], z2);
    }
#pragma unroll
    for (int jj = 0; jj < 8; ++jj) {
      z0 = fmaf(bvv[jj], wB[jj*3+0], z0);
      z1 = fmaf(bvv[jj], wB[jj*3+1], z1);
      z2 = fmaf(bvv[jj], wB[jj*3+2], z2);
    }
#pragma unroll
    for (int off = 32; off > 0; off >>= 1) {
      z0 += __shfl_down(z0, off, 64);
      z1 += __shfl_down(z1, off, 64);
      z2 += __shfl_down(z2, off, 64);
    }
    if (lane == 0) { red[wv][0] = z0; red[wv][1] = z1; red[wv][2] = z2; }
    __syncthreads();
    if (t == 0) {
      float l0 = red[0][0] + red[1][0] + red[2][0] + red[3][0] + bf0 + gum[row*3+0];
      float l1 = red[0][1] + red[1][1] + red[2][1] + red[3][1] + bf1 + gum[row*3+1];
      float l2 = red[0][2] + red[1][2] + red[2][2] + red[3][2] + bf2 + gum[row*3+2];
      int idx = 0; float m = l0;
      if (l1 > m) { m = l1; idx = 1; }
      if (l2 > m) { m = l2; idx = 2; }
      s_idx = idx;
      int pos = atomicAdd(&cnt[idx], 1);
      if (idx == 2) rowl[pos] = row;
    }
    __syncthreads();
    const int idx = s_idx;
    float* po = out + (size_t)row * DMODEL + t * 8;
    if (idx == 0)      { *(float4*)po = av0; *(float4*)(po + 4) = av1; }
    else if (idx == 1) { *(float4*)po = bv0; *(float4*)(po + 4) = bv1; }
    __syncthreads();
  }
}

// ---------------- bf16 split helpers ----------------
__device__ __forceinline__ uint16_t bf16_rn(float x) {
  uint32_t u = __float_as_uint(x);
  u += 0x7fffu + ((u >> 16) & 1u);
  return (uint16_t)(u >> 16);
}
__device__ __forceinline__ float bf16_f(uint16_t h) {
  return __uint_as_float(((uint32_t)h) << 16);
}

// Transpose + split W_share [4096][2048] f32 -> Wt_hi/Wt_lo [2048][4096] bf16,
// PRE-SWIZZLED: within each 64-elem k-tile (128B = 8 chunks of 16B), chunk c of
// row n is stored at position c ^ (n&7). Linear global_load_lds then yields the
// bank-conflict-free layout directly (guideline 21: swizzle source + read, not dest).
__global__ __launch_bounds__(256)
void k_wsplit(const float* __restrict__ Ws, uint16_t* __restrict__ Wh,
              uint16_t* __restrict__ Wl) {
  const int kt = blockIdx.x;        // 64 k-tiles of 64
  const int nb = blockIdx.y;        // 32 n-tiles of 64
  const int k0 = kt << 6, n0 = nb << 6;
  __shared__ float T[64][65];
  const int t = threadIdx.x;
#pragma unroll
  for (int r = 0; r < 4; ++r) {
    int lin = r * 256 + t;
    int ki = lin >> 4;
    int nj = (lin & 15) << 2;
    float4 v = *(const float4*)(Ws + (size_t)(k0 + ki) * DMODEL + n0 + nj);
    T[ki][nj+0] = v.x; T[ki][nj+1] = v.y; T[ki][nj+2] = v.z; T[ki][nj+3] = v.w;
  }
  __syncthreads();
#pragma unroll
  for (int r = 0; r < 4; ++r) {
    int lin = r * 256 + t;
    int nl = lin >> 4;
    int k4 = (lin & 15) << 2;          // 4 consecutive k within one chunk-half
    int ng = n0 + nl;
    int c = k4 >> 3, e0 = k4 & 7;
    float x0 = T[k4+0][nl], x1 = T[k4+1][nl], x2 = T[k4+2][nl], x3 = T[k4+3][nl];
    uint16_t h0 = bf16_rn(x0), h1 = bf16_rn(x1), h2 = bf16_rn(x2), h3 = bf16_rn(x3);
    uint16_t l0 = bf16_rn(x0 - bf16_f(h0)), l1 = bf16_rn(x1 - bf16_f(h1));
    uint16_t l2 = bf16_rn(x2 - bf16_f(h2)), l3 = bf16_rn(x3 - bf16_f(h3));
    size_t off = ((size_t)ng << 12) + k0 + ((size_t)((c ^ (ng & 7)) << 3)) + e0;
    *(uint2*)(Wh + off) = make_uint2((uint32_t)h0 | ((uint32_t)h1 << 16),
                                     (uint32_t)h2 | ((uint32_t)h3 << 16));
    *(uint2*)(Wl + off) = make_uint2((uint32_t)l0 | ((uint32_t)l1 << 16),
                                     (uint32_t)l2 | ((uint32_t)l3 << 16));
  }
}

// bf16x3 split MFMA GEMM over selected rows: out[row] = combined[row]@W_share + b.
// 128x128 tile, BK=64, 4 waves (2x2), 16x16x32 MFMA, 3 products (hh, hl, lh).
__global__ __launch_bounds__(256, 2)
void k_gemm_mfma(const float* __restrict__ a1, const float* __restrict__ a2,
                 const uint16_t* __restrict__ Wh, const uint16_t* __restrict__ Wl,
                 const float* __restrict__ bsh, const int* __restrict__ cnt,
                 const int* __restrict__ rowl, float* __restrict__ out) {
  const int M = cnt[2];
  const int bm = blockIdx.x;
  if (bm * 128 >= M) return;
  const int n0 = blockIdx.y << 7;
  __shared__ uint16_t AhS[128 * 72];    // 144B rows (16B pad): 2-way banks = free
  __shared__ uint16_t AlS[128 * 72];
  __shared__ uint16_t BhS[128 * 64];    // linear 128B rows, data pre-swizzled
  __shared__ uint16_t BlS[128 * 64];
  __shared__ int rows[128];
  const int t = threadIdx.x;
  const int lane = t & 63, w = t >> 6;
  const int wm = w >> 1, wn = w & 1;
  if (t < 128) { int i = bm * 128 + t; rows[t] = (i < M) ? rowl[i] : -1; }
  __syncthreads();

  int arow[8], ak4[8];
#pragma unroll
  for (int r = 0; r < 8; ++r) {
    int lin = r * 256 + t;
    arow[r] = rows[lin >> 4];
    ak4[r] = (lin & 15) << 2;
  }
  f32x4 acc[4][4];
#pragma unroll
  for (int fm = 0; fm < 4; ++fm)
#pragma unroll
    for (int fn = 0; fn < 4; ++fn) acc[fm][fn] = (f32x4){0.f, 0.f, 0.f, 0.f};
  float bias[4];
#pragma unroll
  for (int fn = 0; fn < 4; ++fn)
    bias[fn] = bsh[n0 + (wn << 6) + (fn << 4) + (lane & 15)];

  for (int kt = 0; kt < 64; ++kt) {
    const float* Ab = (kt < 32) ? a1 : a2;
    const int kb = (kt & 31) << 6;
    float4 av[8];
#pragma unroll
    for (int r = 0; r < 8; ++r) {
      av[r] = (arow[r] >= 0)
            ? *(const float4*)(Ab + (size_t)arow[r] * DMODEL + kb + ak4[r])
            : make_float4(0.f, 0.f, 0.f, 0.f);
    }
    __syncthreads();                    // prev iter's LDS reads done
    // B stage: 16KB each of Bh/Bl via global_load_lds (wave-uniform dest + lane*16)
    {
      const int idxb = w << 8;          // this wave's 16B-chunk base (256 chunks/wave... 4KB)
#pragma unroll
      for (int i = 0; i < 4; ++i) {
        int idx16 = idxb + (i << 6) + lane;
        int rb = idx16 >> 3, cc = idx16 & 7;
        size_t goff = ((size_t)(n0 + rb) << 12) + ((size_t)kt << 6) + (cc << 3);
        __builtin_amdgcn_global_load_lds(
            (const __attribute__((address_space(1))) void*)(Wh + goff),
            (__attribute__((address_space(3))) void*)((char*)BhS + (idxb << 4) + (i << 10)),
            16, 0, 0);
        __builtin_amdgcn_global_load_lds(
            (const __attribute__((address_space(1))) void*)(Wl + goff),
            (__attribute__((address_space(3))) void*)((char*)BlS + (idxb << 4) + (i << 10)),
            16, 0, 0);
      }
    }
    // A stage: fp32 -> hi/lo bf16 -> padded LDS
#pragma unroll
    for (int r = 0; r < 8; ++r) {
      int lin = r * 256 + t;
      int mi = lin >> 4;
      const float* xp = (const float*)&av[r];
      uint16_t h[4], l[4];
#pragma unroll
      for (int j = 0; j < 4; ++j) {
        h[j] = bf16_rn(xp[j]);
        l[j] = bf16_rn(xp[j] - bf16_f(h[j]));
      }
      char* pH = (char*)AhS + mi * 144 + (ak4[r] << 1);
      char* pL = (char*)AlS + mi * 144 + (ak4[r] << 1);
      *(uint2*)pH = make_uint2((uint32_t)h[0] | ((uint32_t)h[1] << 16),
                               (uint32_t)h[2] | ((uint32_t)h[3] << 16));
      *(uint2*)pL = make_uint2((uint32_t)l[0] | ((uint32_t)l[1] << 16),
                               (uint32_t)l[2] | ((uint32_t)l[3] << 16));
    }
    __syncthreads();                    // drains vmcnt (gload_lds) + lgkm (ds_write)
#pragma unroll
    for (int ks = 0; ks < 2; ++ks) {
      short8 ah[4], al[4], bh[4], bl[4];
      const int kby = (ks << 6) + ((lane >> 4) << 4);
#pragma unroll
      for (int fm = 0; fm < 4; ++fm) {
        int rm = (wm << 6) + (fm << 4) + (lane & 15);
        ah[fm] = *(const short8*)((const char*)AhS + rm * 144 + kby);
        al[fm] = *(const short8*)((const char*)AlS + rm * 144 + kby);
      }
#pragma unroll
      for (int fn = 0; fn < 4; ++fn) {
        int rn = (wn << 6) + (fn << 4) + (lane & 15);
        int ch = (ks << 2) + (lane >> 4);
        int sw = (ch ^ (rn & 7)) << 4;
        bh[fn] = *(const short8*)((const char*)BhS + rn * 128 + sw);
        bl[fn] = *(const short8*)((const char*)BlS + rn * 128 + sw);
      }
#pragma unroll
      for (int fm = 0; fm < 4; ++fm)
#pragma unroll
        for (int fn = 0; fn < 4; ++fn) {
          f32x4 c = acc[fm][fn];
          c = __builtin_amdgcn_mfma_f32_16x16x32_bf16(ah[fm], bh[fn], c, 0, 0, 0);
          c = __builtin_amdgcn_mfma_f32_16x16x32_bf16(ah[fm], bl[fn], c, 0, 0, 0);
          c = __builtin_amdgcn_mfma_f32_16x16x32_bf16(al[fm], bh[fn], c, 0, 0, 0);
          acc[fm][fn] = c;
        }
    }
  }
  // epilogue: C/D layout col=lane&15, row=(lane>>4)*4+j  [m89-verified]
#pragma unroll
  for (int fm = 0; fm < 4; ++fm) {
    int rbase = (wm << 6) + (fm << 4) + ((lane >> 4) << 2);
#pragma unroll
    for (int j = 0; j < 4; ++j) {
      int row = rows[rbase + j];
      if (row < 0) continue;
      float* po = out + (size_t)row * DMODEL + n0 + (wn << 6) + (lane & 15);
#pragma unroll
      for (int fn = 0; fn < 4; ++fn)
        po[fn << 4] = acc[fm][fn][j] + bias[fn];
    }
  }
}

// fallback fp32 GEMM (used only if ws too small for the split-W buffers)
#define BM 128
#define BN 128
#define BK 32
__global__ __launch_bounds__(256)
void k_gemm_f32(const float* __restrict__ a1, const float* __restrict__ a2,
                const float* __restrict__ Ws, const float* __restrict__ bsh,
                const int* __restrict__ cnt, const int* __restrict__ rowl,
                float* __restrict__ out) {
  const int M = cnt[2];
  const int bm = blockIdx.x;
  if (bm * BM >= M) return;
  const int bn = blockIdx.y;
  __shared__ float As[BK][132];
  __shared__ float Bs[BK][128];
  __shared__ int rows[BM];
  const int t = threadIdx.x;
  if (t < BM) {
    int i = bm * BM + t;
    rows[t] = (i < M) ? rowl[i] : -1;
  }
  __syncthreads();
  float acc[8][8];
#pragma unroll
  for (int i = 0; i < 8; ++i)
#pragma unroll
    for (int j = 0; j < 8; ++j) acc[i][j] = 0.f;
  const int tx = t & 15, ty = t >> 4;
  for (int k0 = 0; k0 < DIN; k0 += BK) {
    const float* Abase = (k0 < DMODEL) ? a1 : a2;
    const int kb = (k0 < DMODEL) ? k0 : (k0 - DMODEL);
    float4 av[4], bv4[4];
#pragma unroll
    for (int r = 0; r < 4; ++r) {
      int lin = r * 256 + t;
      int mi = lin >> 3;
      int ki = (lin & 7) << 2;
      int row = rows[mi];
      av[r] = (row >= 0) ? *(const float4*)(Abase + (size_t)row * DMODEL + kb + ki)
                         : make_float4(0.f, 0.f, 0.f, 0.f);
    }
#pragma unroll
    for (int r = 0; r < 4; ++r) {
      int lin = r * 256 + t;
      int ki = lin >> 5;
      int ni = (lin & 31) << 2;
      bv4[r] = *(const float4*)(Ws + (size_t)(k0 + ki) * DMODEL + bn * BN + ni);
    }
    __syncthreads();
#pragma unroll
    for (int r = 0; r < 4; ++r) {
      int lin = r * 256 + t;
      int mi = lin >> 3;
      int ki = (lin & 7) << 2;
      As[ki + 0][mi] = av[r].x;
      As[ki + 1][mi] = av[r].y;
      As[ki + 2][mi] = av[r].z;
      As[ki + 3][mi] = av[r].w;
      int k2 = lin >> 5;
      int ni = (lin & 31) << 2;
      *(float4*)(&Bs[k2][ni]) = bv4[r];
    }
    __syncthreads();
#pragma unroll
    for (int kk = 0; kk < BK; ++kk) {
      float4 aL = *(const float4*)(&As[kk][ty << 2]);
      float4 aH = *(const float4*)(&As[kk][64 + (ty << 2)]);
      float4 bL = *(const float4*)(&Bs[kk][tx << 2]);
      float4 bH = *(const float4*)(&Bs[kk][64 + (tx << 2)]);
      float am[8] = {aL.x, aL.y, aL.z, aL.w, aH.x, aH.y, aH.z, aH.w};
      float bb[8] = {bL.x, bL.y, bL.z, bL.w, bH.x, bH.y, bH.z, bH.w};
#pragma unroll
      for (int i = 0; i < 8; ++i)
#pragma unroll
        for (int j = 0; j < 8; ++j)
          acc[i][j] = fmaf(am[i], bb[j], acc[i][j]);
    }
  }
  float bias[8];
#pragma unroll
  for (int j = 0; j < 4; ++j) {
    bias[j]     = bsh[bn * BN + (tx << 2) + j];
    bias[4 + j] = bsh[bn * BN + 64 + (tx << 2) + j];
  }
#pragma unroll
  for (int i = 0; i < 8; ++i) {
    int m = (i < 4) ? ((ty << 2) + i) : (64 + (ty << 2) + (i - 4));
    int row = rows[m];
    if (row < 0) continue;
    float* po = out + (size_t)row * DMODEL + bn * BN;
    float4 v0 = make_float4(acc[i][0] + bias[0], acc[i][1] + bias[1],
                            acc[i][2] + bias[2], acc[i][3] + bias[3]);
    float4 v1 = make_float4(acc[i][4] + bias[4], acc[i][5] + bias[5],
                            acc[i][6] + bias[6], acc[i][7] + bias[7]);
    *(float4*)(po + (tx << 2)) = v0;
    *(float4*)(po + 64 + (tx << 2)) = v1;
  }
}

__global__ void k_loss(const int* __restrict__ cnt, float* __restrict__ o) {
  if (threadIdx.x == 0 && blockIdx.x == 0) {
    const float inv = 1.0f / (float)NROWS;
    float lb = 0.f;
#pragma unroll
    for (int e = 0; e < 3; ++e) {
      float m = (float)cnt[e] * inv;
      lb -= m * logf(m + 1e-8f);
    }
    o[0] = 0.0f;
    o[1] = lb;
  }
}

extern "C" void kernel_launch(void* const* d_in, const int* in_sizes, int n_in,
                              void* d_out, int out_size, void* d_ws, size_t ws_size,
                              hipStream_t stream) {
  const float* a1  = (const float*)d_in[0];
  const float* a2  = (const float*)d_in[1];
  const float* Ws  = (const float*)d_in[2];
  const float* bsh = (const float*)d_in[3];
  const float* Wr  = (const float*)d_in[4];
  const float* br  = (const float*)d_in[5];
  float* out = (float*)d_out;
  char* ws = (char*)d_ws;
  int*      cnt  = (int*)(ws + WS_CNT);
  float*    bf   = (float*)(ws + WS_BF);
  float*    Wf   = (float*)(ws + WS_WF);
  float*    gum  = (float*)(ws + WS_GUM);
  int*      rowl = (int*)(ws + WS_ROWL);
  uint16_t* Wh   = (uint16_t*)(ws + WS_WTH);
  uint16_t* Wl   = (uint16_t*)(ws + WS_WTL);
  float* losses = out + (size_t)NROWS * DMODEL;
  const bool bigws = ws_size >= WS_NEED;

  hipLaunchKernelGGL(k_init,   dim3(1),              dim3(64),  0, stream, cnt);
  hipLaunchKernelGGL(k_gumbel, dim3((NG + 255)/256), dim3(256), 0, stream, gum);
  hipLaunchKernelGGL(k_wfused, dim3(DIN + 1),        dim3(256), 0, stream, Ws, bsh, Wr, br, Wf, bf);
  if (bigws)
    hipLaunchKernelGGL(k_wsplit, dim3(64, 32),       dim3(256), 0, stream, Ws, Wh, Wl);
  hipLaunchKernelGGL(k_router, dim3(NROWS / RPB),    dim3(256), 0, stream, a1, a2, Wf, bf, gum, out, cnt, rowl);
  if (bigws)
    hipLaunchKernelGGL(k_gemm_mfma, dim3(NROWS / 128, DMODEL / 128), dim3(256), 0, stream,
                       a1, a2, Wh, Wl, bsh, cnt, rowl, out);
  else
    hipLaunchKernelGGL(k_gemm_f32, dim3(NROWS / BM, DMODEL / BN), dim3(256), 0, stream,
                       a1, a2, Ws, bsh, cnt, rowl, out);
  hipLaunchKernelGGL(k_loss,   dim3(1),              dim3(64),  0, stream, cnt, losses);
}

// Round 3
// 413.553 us; speedup vs baseline: 4.3226x; 1.4842x over previous
//
#include <hip/hip_runtime.h>
#include <hip/hip_fp16.h>
#include <stdint.h>

// ---------------- problem constants ----------------
#define NROWS  16384      // B*S
#define DMODEL 2048
#define DIN    4096
#define NG     (NROWS*3)

// ---------------- workspace layout (bytes) ----------------
#define WS_CNT   0
#define WS_BF    256
#define WS_WF    512
#define WS_GUM   65536
#define WS_ROWL  262144
#define WS_WH    (1u<<20)                  // W^T hi fp16 [2048][4096], pre-swizzled
#define WS_WL    (WS_WH + (16u<<20))       // W^T lo fp16
#define WS_ACOMP (WS_WL + (16u<<20))       // compacted A fp16 [capRows][4096], pre-swizzled

typedef __attribute__((ext_vector_type(8))) _Float16 f16x8;
typedef __attribute__((ext_vector_type(4))) float f32x4;

#define THREEFRY_PARTITIONABLE 1

__device__ __forceinline__ void tf2x32(uint32_t k0, uint32_t k1,
                                       uint32_t x0, uint32_t x1,
                                       uint32_t& o0, uint32_t& o1) {
  uint32_t k2 = k0 ^ k1 ^ 0x1BD11BDAu;
  x0 += k0; x1 += k1;
#define TFR(r) { x0 += x1; x1 = (x1 << r) | (x1 >> (32 - r)); x1 ^= x0; }
  TFR(13) TFR(15) TFR(26) TFR(6)
  x0 += k1; x1 += k2 + 1u;
  TFR(17) TFR(29) TFR(16) TFR(24)
  x0 += k2; x1 += k0 + 2u;
  TFR(13) TFR(15) TFR(26) TFR(6)
  x0 += k0; x1 += k1 + 3u;
  TFR(17) TFR(29) TFR(16) TFR(24)
  x0 += k1; x1 += k2 + 4u;
  TFR(13) TFR(15) TFR(26) TFR(6)
  x0 += k2; x1 += k0 + 5u;
#undef TFR
  o0 = x0; o1 = x1;
}

__global__ void k_init(int* __restrict__ cnt) {
  if (threadIdx.x < 8) cnt[threadIdx.x] = 0;
}

__global__ void k_gumbel(float* __restrict__ g) {
  int j = blockIdx.x * blockDim.x + threadIdx.x;
  if (j >= NG) return;
  uint32_t b0, b1, bits;
#if THREEFRY_PARTITIONABLE
  tf2x32(0u, 42u, 0u, (uint32_t)j, b0, b1);
  bits = b0 ^ b1;
#else
  const int half = NG / 2;
  if (j < half) { tf2x32(0u, 42u, (uint32_t)j, (uint32_t)(j + half), b0, b1); bits = b0; }
  else          { tf2x32(0u, 42u, (uint32_t)(j - half), (uint32_t)j, b0, b1); bits = b1; }
#endif
  float U = __uint_as_float((bits >> 9) | 0x3f800000u) - 1.0f;
  U = fmaxf(U, 1e-10f);
  U = fminf(U, 1.0f);
  g[j] = -logf(-logf(U));
}

__global__ __launch_bounds__(256)
void k_wfused(const float* __restrict__ Ws, const float* __restrict__ bsh,
              const float* __restrict__ Wr, const float* __restrict__ br,
              float* __restrict__ Wf, float* __restrict__ bf) {
  const int k = blockIdx.x;
  const int t = threadIdx.x;
  const float* src = (k < DIN) ? (Ws + (size_t)k * DMODEL) : bsh;
  float4 x0 = *(const float4*)(src + t * 8);
  float4 x1 = *(const float4*)(src + t * 8 + 4);
  float xv[8] = {x0.x, x0.y, x0.z, x0.w, x1.x, x1.y, x1.z, x1.w};
  float4 w4[6];
  const float4* wp = (const float4*)(Wr + t * 24);
#pragma unroll
  for (int i = 0; i < 6; ++i) w4[i] = wp[i];
  const float* wfv = (const float*)w4;
  float z0 = 0.f, z1 = 0.f, z2 = 0.f;
#pragma unroll
  for (int jj = 0; jj < 8; ++jj) {
    z0 = fmaf(xv[jj], wfv[jj*3+0], z0);
    z1 = fmaf(xv[jj], wfv[jj*3+1], z1);
    z2 = fmaf(xv[jj], wfv[jj*3+2], z2);
  }
#pragma unroll
  for (int off = 32; off > 0; off >>= 1) {
    z0 += __shfl_down(z0, off, 64);
    z1 += __shfl_down(z1, off, 64);
    z2 += __shfl_down(z2, off, 64);
  }
  __shared__ float red[4][3];
  int lane = t & 63, wv = t >> 6;
  if (lane == 0) { red[wv][0] = z0; red[wv][1] = z1; red[wv][2] = z2; }
  __syncthreads();
  if (t == 0) {
    float s0 = red[0][0] + red[1][0] + red[2][0] + red[3][0];
    float s1 = red[0][1] + red[1][1] + red[2][1] + red[3][1];
    float s2 = red[0][2] + red[1][2] + red[2][2] + red[3][2];
    if (k < DIN) { Wf[k*3+0] = s0; Wf[k*3+1] = s1; Wf[k*3+2] = s2; }
    else { bf[0] = s0 + br[0]; bf[1] = s1 + br[1]; bf[2] = s2 + br[2]; }
  }
}

// ---------------- fp16 helpers (RNE) ----------------
__device__ __forceinline__ uint16_t f16b(float x) {
  return __half_as_ushort(__float2half(x));
}
__device__ __forceinline__ float f16v(uint16_t u) {
  return __half2float(__ushort_as_half(u));
}

// Transpose + split W_share [4096][2048] f32 -> Wh/Wl [2048][4096] fp16,
// pre-swizzled: within each 64-elem k-group (128B = 8 chunks of 16B), chunk c of
// row n stored at c ^ (n&7). Linear global_load_lds then yields the
// conflict-free layout (guideline 21).
__global__ __launch_bounds__(256)
void k_wsplit(const float* __restrict__ Ws, uint16_t* __restrict__ Wh,
              uint16_t* __restrict__ Wl) {
  const int kt = blockIdx.x;        // 64 k-tiles of 64
  const int nb = blockIdx.y;        // 32 n-tiles of 64
  const int k0 = kt << 6, n0 = nb << 6;
  __shared__ float T[64][65];
  const int t = threadIdx.x;
#pragma unroll
  for (int r = 0; r < 4; ++r) {
    int lin = r * 256 + t;
    int ki = lin >> 4;
    int nj = (lin & 15) << 2;
    float4 v = *(const float4*)(Ws + (size_t)(k0 + ki) * DMODEL + n0 + nj);
    T[ki][nj+0] = v.x; T[ki][nj+1] = v.y; T[ki][nj+2] = v.z; T[ki][nj+3] = v.w;
  }
  __syncthreads();
#pragma unroll
  for (int r = 0; r < 4; ++r) {
    int lin = r * 256 + t;
    int nl = lin >> 4;
    int k4 = (lin & 15) << 2;
    int ng = n0 + nl;
    int c = k4 >> 3, e0 = k4 & 7;
    float x0 = T[k4+0][nl], x1 = T[k4+1][nl], x2 = T[k4+2][nl], x3 = T[k4+3][nl];
    uint16_t h0 = f16b(x0), h1 = f16b(x1), h2 = f16b(x2), h3 = f16b(x3);
    uint16_t l0 = f16b(x0 - f16v(h0)), l1 = f16b(x1 - f16v(h1));
    uint16_t l2 = f16b(x2 - f16v(h2)), l3 = f16b(x3 - f16v(h3));
    size_t off = ((size_t)ng << 12) + k0 + ((size_t)((c ^ (ng & 7)) << 3)) + e0;
    *(uint2*)(Wh + off) = make_uint2((uint32_t)h0 | ((uint32_t)h1 << 16),
                                     (uint32_t)h2 | ((uint32_t)h3 << 16));
    *(uint2*)(Wl + off) = make_uint2((uint32_t)l0 | ((uint32_t)l1 << 16),
                                     (uint32_t)l2 | ((uint32_t)l3 << 16));
  }
}

// Router: logits + argmax; idx 0/1 rows written directly; idx==2 rows appended
// to rowl AND written as pre-swizzled fp16 into Acomp (fused compaction).
#define RPB 8
__global__ __launch_bounds__(256)
void k_router(const float* __restrict__ a1, const float* __restrict__ a2,
              const float* __restrict__ Wf, const float* __restrict__ bf,
              const float* __restrict__ gum,
              float* __restrict__ out, int* __restrict__ cnt,
              int* __restrict__ rowl, uint16_t* __restrict__ acomp, int cap) {
  const int t = threadIdx.x;
  float wA[24], wB[24];
  {
    float4 q[6];
    const float4* p = (const float4*)(Wf + t * 24);
#pragma unroll
    for (int i = 0; i < 6; ++i) q[i] = p[i];
#pragma unroll
    for (int i = 0; i < 24; ++i) wA[i] = ((const float*)q)[i];
    const float4* p2 = (const float4*)(Wf + (size_t)DMODEL * 3 + t * 24);
#pragma unroll
    for (int i = 0; i < 6; ++i) q[i] = p2[i];
#pragma unroll
    for (int i = 0; i < 24; ++i) wB[i] = ((const float*)q)[i];
  }
  const float bf0 = bf[0], bf1 = bf[1], bf2 = bf[2];
  __shared__ float red[4][3];
  __shared__ int s_idx, s_pos;
  const int lane = t & 63, wv = t >> 6;

  for (int rr = 0; rr < RPB; ++rr) {
    const int row = blockIdx.x * RPB + rr;
    const float* pa = a1 + (size_t)row * DMODEL + t * 8;
    const float* pb = a2 + (size_t)row * DMODEL + t * 8;
    float4 av0 = *(const float4*)pa, av1 = *(const float4*)(pa + 4);
    float4 bv0 = *(const float4*)pb, bv1 = *(const float4*)(pb + 4);
    float avv[8] = {av0.x, av0.y, av0.z, av0.w, av1.x, av1.y, av1.z, av1.w};
    float bvv[8] = {bv0.x, bv0.y, bv0.z, bv0.w, bv1.x, bv1.y, bv1.z, bv1.w};
    float z0 = 0.f, z1 = 0.f, z2 = 0.f;
#pragma unroll
    for (int jj = 0; jj < 8; ++jj) {
      z0 = fmaf(avv[jj], wA[jj*3+0], z0);
      z1 = fmaf(avv[jj], wA[jj*3+1], z1);
      z2 = fmaf(avv[jj], wA[jj*3+2], z2);
    }
#pragma unroll
    for (int jj = 0; jj < 8; ++jj) {
      z0 = fmaf(bvv[jj], wB[jj*3+0], z0);
      z1 = fmaf(bvv[jj], wB[jj*3+1], z1);
      z2 = fmaf(bvv[jj], wB[jj*3+2], z2);
    }
#pragma unroll
    for (int off = 32; off > 0; off >>= 1) {
      z0 += __shfl_down(z0, off, 64);
      z1 += __shfl_down(z1, off, 64);
      z2 += __shfl_down(z2, off, 64);
    }
    if (lane == 0) { red[wv][0] = z0; red[wv][1] = z1; red[wv][2] = z2; }
    __syncthreads();
    if (t == 0) {
      float l0 = red[0][0] + red[1][0] + red[2][0] + red[3][0] + bf0 + gum[row*3+0];
      float l1 = red[0][1] + red[1][1] + red[2][1] + red[3][1] + bf1 + gum[row*3+1];
      float l2 = red[0][2] + red[1][2] + red[2][2] + red[3][2] + bf2 + gum[row*3+2];
      int idx = 0; float m = l0;
      if (l1 > m) { m = l1; idx = 1; }
      if (l2 > m) { m = l2; idx = 2; }
      s_idx = idx;
      int pos = atomicAdd(&cnt[idx], 1);
      s_pos = pos;
      if (idx == 2) rowl[pos] = row;
    }
    __syncthreads();
    const int idx = s_idx;
    if (idx == 0) {
      float* po = out + (size_t)row * DMODEL + t * 8;
      *(float4*)po = av0; *(float4*)(po + 4) = av1;
    } else if (idx == 1) {
      float* po = out + (size_t)row * DMODEL + t * 8;
      *(float4*)po = bv0; *(float4*)(po + 4) = bv1;
    } else {
      const int p = s_pos;
      if (p < cap) {
        uint16_t* ar = acomp + ((size_t)p << 12);
        int goff = ((t >> 3) << 6) + ((((t & 7) ^ (p & 7))) << 3);
        uint32_t q0 = (uint32_t)f16b(avv[0]) | ((uint32_t)f16b(avv[1]) << 16);
        uint32_t q1 = (uint32_t)f16b(avv[2]) | ((uint32_t)f16b(avv[3]) << 16);
        uint32_t q2 = (uint32_t)f16b(avv[4]) | ((uint32_t)f16b(avv[5]) << 16);
        uint32_t q3 = (uint32_t)f16b(avv[6]) | ((uint32_t)f16b(avv[7]) << 16);
        *(uint4*)(ar + goff) = make_uint4(q0, q1, q2, q3);
        q0 = (uint32_t)f16b(bvv[0]) | ((uint32_t)f16b(bvv[1]) << 16);
        q1 = (uint32_t)f16b(bvv[2]) | ((uint32_t)f16b(bvv[3]) << 16);
        q2 = (uint32_t)f16b(bvv[4]) | ((uint32_t)f16b(bvv[5]) << 16);
        q3 = (uint32_t)f16b(bvv[6]) | ((uint32_t)f16b(bvv[7]) << 16);
        *(uint4*)(ar + 2048 + goff) = make_uint4(q0, q1, q2, q3);
      }
    }
    __syncthreads();
  }
}

// fp16 2-product MFMA GEMM over selected rows: out[row] = combined[row]@W + b.
// 128x128 tile, BK=64, 4 waves (2x2), mfma_f32_16x16x32_f16, C = A*(Wh + Wl).
// AMODE 0: A staged via global_load_lds from pre-swizzled Acomp.
// AMODE 1: A gathered from a1/a2 fp32, converted and ds_written (overflow path).
template<int AMODE>
__global__ __launch_bounds__(256, 3)
void k_gemm_fp16(const float* __restrict__ a1, const float* __restrict__ a2,
                 const uint16_t* __restrict__ Acomp,
                 const uint16_t* __restrict__ Wh, const uint16_t* __restrict__ Wl,
                 const float* __restrict__ bsh, const int* __restrict__ cnt,
                 const int* __restrict__ rowl, float* __restrict__ out,
                 int capRows) {
  const int M = cnt[2];
  const int nwg = (int)gridDim.x;
  const int mTiles = nwg >> 4;
  // m204 bijective XCD remap, then bm-major decode (XCD chunk shares bn panels)
  int xcd = blockIdx.x & 7, rest = blockIdx.x >> 3;
  int q = nwg >> 3, r = nwg & 7;
  int swz = (xcd < r ? xcd * (q + 1) : r * (q + 1) + (xcd - r) * q) + rest;
  const int bm = swz % mTiles;
  const int bn = swz / mTiles;
  if (bm * 128 >= M) return;
  if (AMODE == 1 && bm * 128 < capRows) return;
  const int n0 = bn << 7;

  __shared__ uint16_t AS[128 * 64];
  __shared__ uint16_t BhS[128 * 64];
  __shared__ uint16_t BlS[128 * 64];
  __shared__ int rows[128];
  const int t = threadIdx.x;
  const int lane = t & 63, w = t >> 6;
  const int wm = w >> 1, wn = w & 1;
  if (t < 128) { int i = bm * 128 + t; rows[t] = (i < M) ? rowl[i] : -1; }
  __syncthreads();

  f32x4 acc[4][4];
#pragma unroll
  for (int fm = 0; fm < 4; ++fm)
#pragma unroll
    for (int fn = 0; fn < 4; ++fn) acc[fm][fn] = (f32x4){0.f, 0.f, 0.f, 0.f};
  float bias[4];
#pragma unroll
  for (int fn = 0; fn < 4; ++fn)
    bias[fn] = bsh[n0 + (wn << 6) + (fn << 4) + (lane & 15)];

  const size_t arow0 = ((size_t)(bm << 7)) << 12;   // (bm*128)*4096 elems

  for (int kt = 0; kt < 64; ++kt) {
    __syncthreads();                 // prior iter's LDS reads done
    // ---- B stage: Wh/Wl, 16 KiB each, linear LDS dest (source pre-swizzled)
#pragma unroll
    for (int i = 0; i < 4; ++i) {
      int idx = (w << 8) + (i << 6) + lane;
      int nrow = idx >> 3, c = idx & 7;
      size_t goff = ((size_t)(n0 + nrow) << 12) + (kt << 6) + (c << 3);
      __builtin_amdgcn_global_load_lds(
          (const __attribute__((address_space(1))) void*)(Wh + goff),
          (__attribute__((address_space(3))) void*)((char*)BhS + (w << 12) + (i << 10)),
          16, 0, 0);
      __builtin_amdgcn_global_load_lds(
          (const __attribute__((address_space(1))) void*)(Wl + goff),
          (__attribute__((address_space(3))) void*)((char*)BlS + (w << 12) + (i << 10)),
          16, 0, 0);
    }
    // ---- A stage
    if (AMODE == 0) {
#pragma unroll
      for (int i = 0; i < 4; ++i) {
        int idx = (w << 8) + (i << 6) + lane;
        int m = idx >> 3, c = idx & 7;
        const uint16_t* src = Acomp + arow0 + (((size_t)m) << 12) + (kt << 6) + (c << 3);
        __builtin_amdgcn_global_load_lds(
            (const __attribute__((address_space(1))) void*)src,
            (__attribute__((address_space(3))) void*)((char*)AS + (w << 12) + (i << 10)),
            16, 0, 0);
      }
    } else {
#pragma unroll
      for (int i = 0; i < 4; ++i) {
        int idx = t + (i << 8);
        int m = idx >> 3, c = idx & 7;
        int row = rows[m];
        float4 v0 = make_float4(0.f,0.f,0.f,0.f), v1 = v0;
        if (row >= 0) {
          const float* s = (kt < 32)
              ? (a1 + (size_t)row * DMODEL + (kt << 6) + (c << 3))
              : (a2 + (size_t)row * DMODEL + ((kt - 32) << 6) + (c << 3));
          v0 = *(const float4*)s; v1 = *(const float4*)(s + 4);
        }
        uint32_t q0 = (uint32_t)f16b(v0.x) | ((uint32_t)f16b(v0.y) << 16);
        uint32_t q1 = (uint32_t)f16b(v0.z) | ((uint32_t)f16b(v0.w) << 16);
        uint32_t q2 = (uint32_t)f16b(v1.x) | ((uint32_t)f16b(v1.y) << 16);
        uint32_t q3 = (uint32_t)f16b(v1.z) | ((uint32_t)f16b(v1.w) << 16);
        *(uint4*)((char*)AS + m * 128 + ((c ^ (m & 7)) << 4)) = make_uint4(q0, q1, q2, q3);
      }
    }
    __syncthreads();                 // drain vmcnt (gload_lds) + lgkm (ds_write)
    // ---- compute: 2 k-slices x 4x4 frags x 2 products
#pragma unroll
    for (int ks = 0; ks < 2; ++ks) {
      const int chb = (ks << 2) | (lane >> 4);
      f16x8 af[4];
#pragma unroll
      for (int fm = 0; fm < 4; ++fm) {
        int rm = (wm << 6) + (fm << 4) + (lane & 15);
        af[fm] = *(const f16x8*)((const char*)AS + rm * 128 + ((chb ^ (rm & 7)) << 4));
      }
#pragma unroll
      for (int fn = 0; fn < 4; ++fn) {
        int rn = (wn << 6) + (fn << 4) + (lane & 15);
        int sw = (chb ^ (rn & 7)) << 4;
        f16x8 bh = *(const f16x8*)((const char*)BhS + rn * 128 + sw);
        f16x8 bl = *(const f16x8*)((const char*)BlS + rn * 128 + sw);
#pragma unroll
        for (int fm = 0; fm < 4; ++fm) {
          acc[fm][fn] = __builtin_amdgcn_mfma_f32_16x16x32_f16(af[fm], bh, acc[fm][fn], 0, 0, 0);
          acc[fm][fn] = __builtin_amdgcn_mfma_f32_16x16x32_f16(af[fm], bl, acc[fm][fn], 0, 0, 0);
        }
      }
    }
  }
  // epilogue: C/D layout col=lane&15, row=(lane>>4)*4+j
#pragma unroll
  for (int fm = 0; fm < 4; ++fm) {
    int rbase = (wm << 6) + (fm << 4) + ((lane >> 4) << 2);
#pragma unroll
    for (int j = 0; j < 4; ++j) {
      int row = rows[rbase + j];
      if (row < 0) continue;
      float* po = out + (size_t)row * DMODEL + n0 + (wn << 6) + (lane & 15);
#pragma unroll
      for (int fn = 0; fn < 4; ++fn)
        po[fn << 4] = acc[fm][fn][j] + bias[fn];
    }
  }
}

// fp32 fallback GEMM (only if ws too small for Wh/Wl)
#define BM 128
#define BN 128
#define BK 32
__global__ __launch_bounds__(256)
void k_gemm_f32(const float* __restrict__ a1, const float* __restrict__ a2,
                const float* __restrict__ Ws, const float* __restrict__ bsh,
                const int* __restrict__ cnt, const int* __restrict__ rowl,
                float* __restrict__ out) {
  const int M = cnt[2];
  const int bm = blockIdx.x;
  if (bm * BM >= M) return;
  const int bn = blockIdx.y;
  __shared__ float As[BK][132];
  __shared__ float Bs[BK][128];
  __shared__ int rows[BM];
  const int t = threadIdx.x;
  if (t < BM) {
    int i = bm * BM + t;
    rows[t] = (i < M) ? rowl[i] : -1;
  }
  __syncthreads();
  float acc[8][8];
#pragma unroll
  for (int i = 0; i < 8; ++i)
#pragma unroll
    for (int j = 0; j < 8; ++j) acc[i][j] = 0.f;
  const int tx = t & 15, ty = t >> 4;
  for (int k0 = 0; k0 < DIN; k0 += BK) {
    const float* Abase = (k0 < DMODEL) ? a1 : a2;
    const int kb = (k0 < DMODEL) ? k0 : (k0 - DMODEL);
    float4 av[4], bv4[4];
#pragma unroll
    for (int r = 0; r < 4; ++r) {
      int lin = r * 256 + t;
      int mi = lin >> 3;
      int ki = (lin & 7) << 2;
      int row = rows[mi];
      av[r] = (row >= 0) ? *(const float4*)(Abase + (size_t)row * DMODEL + kb + ki)
                         : make_float4(0.f, 0.f, 0.f, 0.f);
    }
#pragma unroll
    for (int r = 0; r < 4; ++r) {
      int lin = r * 256 + t;
      int ki = lin >> 5;
      int ni = (lin & 31) << 2;
      bv4[r] = *(const float4*)(Ws + (size_t)(k0 + ki) * DMODEL + bn * BN + ni);
    }
    __syncthreads();
#pragma unroll
    for (int r = 0; r < 4; ++r) {
      int lin = r * 256 + t;
      int mi = lin >> 3;
      int ki = (lin & 7) << 2;
      As[ki + 0][mi] = av[r].x;
      As[ki + 1][mi] = av[r].y;
      As[ki + 2][mi] = av[r].z;
      As[ki + 3][mi] = av[r].w;
      int k2 = lin >> 5;
      int ni = (lin & 31) << 2;
      *(float4*)(&Bs[k2][ni]) = bv4[r];
    }
    __syncthreads();
#pragma unroll
    for (int kk = 0; kk < BK; ++kk) {
      float4 aL = *(const float4*)(&As[kk][ty << 2]);
      float4 aH = *(const float4*)(&As[kk][64 + (ty << 2)]);
      float4 bL = *(const float4*)(&Bs[kk][tx << 2]);
      float4 bH = *(const float4*)(&Bs[kk][64 + (tx << 2)]);
      float am[8] = {aL.x, aL.y, aL.z, aL.w, aH.x, aH.y, aH.z, aH.w};
      float bb[8] = {bL.x, bL.y, bL.z, bL.w, bH.x, bH.y, bH.z, bH.w};
#pragma unroll
      for (int i = 0; i < 8; ++i)
#pragma unroll
        for (int j = 0; j < 8; ++j)
          acc[i][j] = fmaf(am[i], bb[j], acc[i][j]);
    }
  }
  float bias[8];
#pragma unroll
  for (int j = 0; j < 4; ++j) {
    bias[j]     = bsh[bn * BN + (tx << 2) + j];
    bias[4 + j] = bsh[bn * BN + 64 + (tx << 2) + j];
  }
#pragma unroll
  for (int i = 0; i < 8; ++i) {
    int m = (i < 4) ? ((ty << 2) + i) : (64 + (ty << 2) + (i - 4));
    int row = rows[m];
    if (row < 0) continue;
    float* po = out + (size_t)row * DMODEL + bn * BN;
    float4 v0 = make_float4(acc[i][0] + bias[0], acc[i][1] + bias[1],
                            acc[i][2] + bias[2], acc[i][3] + bias[3]);
    float4 v1 = make_float4(acc[i][4] + bias[4], acc[i][5] + bias[5],
                            acc[i][6] + bias[6], acc[i][7] + bias[7]);
    *(float4*)(po + (tx << 2)) = v0;
    *(float4*)(po + 64 + (tx << 2)) = v1;
  }
}

__global__ void k_loss(const int* __restrict__ cnt, float* __restrict__ o) {
  if (threadIdx.x == 0 && blockIdx.x == 0) {
    const float inv = 1.0f / (float)NROWS;
    float lb = 0.f;
#pragma unroll
    for (int e = 0; e < 3; ++e) {
      float m = (float)cnt[e] * inv;
      lb -= m * logf(m + 1e-8f);
    }
    o[0] = 0.0f;
    o[1] = lb;
  }
}

extern "C" void kernel_launch(void* const* d_in, const int* in_sizes, int n_in,
                              void* d_out, int out_size, void* d_ws, size_t ws_size,
                              hipStream_t stream) {
  const float* a1  = (const float*)d_in[0];
  const float* a2  = (const float*)d_in[1];
  const float* Ws  = (const float*)d_in[2];
  const float* bsh = (const float*)d_in[3];
  const float* Wr  = (const float*)d_in[4];
  const float* br  = (const float*)d_in[5];
  float* out = (float*)d_out;
  char* ws = (char*)d_ws;
  int*      cnt   = (int*)(ws + WS_CNT);
  float*    bf    = (float*)(ws + WS_BF);
  float*    Wf    = (float*)(ws + WS_WF);
  float*    gum   = (float*)(ws + WS_GUM);
  int*      rowl  = (int*)(ws + WS_ROWL);
  uint16_t* Wh    = (uint16_t*)(ws + WS_WH);
  uint16_t* Wl    = (uint16_t*)(ws + WS_WL);
  uint16_t* Acomp = (uint16_t*)(ws + WS_ACOMP);
  float* losses = out + (size_t)NROWS * DMODEL;

  const bool fp16path = ws_size >= (size_t)WS_ACOMP;
  int capRows = 0;
  if (fp16path) {
    size_t avail = ws_size - (size_t)WS_ACOMP;
    size_t capT = (avail >> 13) >> 7;             // rows/128
    if (capT > 128) capT = 128;
    capRows = (int)(capT << 7);
  }

  hipLaunchKernelGGL(k_init,   dim3(1),              dim3(64),  0, stream, cnt);
  hipLaunchKernelGGL(k_gumbel, dim3((NG + 255)/256), dim3(256), 0, stream, gum);
  hipLaunchKernelGGL(k_wfused, dim3(DIN + 1),        dim3(256), 0, stream, Ws, bsh, Wr, br, Wf, bf);
  if (fp16path) {
    hipLaunchKernelGGL(k_wsplit, dim3(64, 32),       dim3(256), 0, stream, Ws, Wh, Wl);
    hipLaunchKernelGGL(k_router, dim3(NROWS / RPB),  dim3(256), 0, stream,
                       a1, a2, Wf, bf, gum, out, cnt, rowl, Acomp, capRows);
    if (capRows > 0)
      hipLaunchKernelGGL((k_gemm_fp16<0>), dim3((capRows / 128) * 16), dim3(256), 0, stream,
                         a1, a2, Acomp, Wh, Wl, bsh, cnt, rowl, out, capRows);
    if (capRows < NROWS)
      hipLaunchKernelGGL((k_gemm_fp16<1>), dim3((NROWS / 128) * 16), dim3(256), 0, stream,
                         a1, a2, Acomp, Wh, Wl, bsh, cnt, rowl, out, capRows);
  } else {
    hipLaunchKernelGGL(k_router, dim3(NROWS / RPB),  dim3(256), 0, stream,
                       a1, a2, Wf, bf, gum, out, cnt, rowl, (uint16_t*)nullptr, 0);
    hipLaunchKernelGGL(k_gemm_f32, dim3(NROWS / BM, DMODEL / BN), dim3(256), 0, stream,
                       a1, a2, Ws, bsh, cnt, rowl, out);
  }
  hipLaunchKernelGGL(k_loss,   dim3(1),              dim3(64),  0, stream, cnt, losses);
}